// Round 6
// baseline (54990.442 us; speedup 1.0000x reference)
//
#include <hip/hip_runtime.h>
#include <math.h>

#define BB 128
#define TT 256
#define HH 512
#define VV 32
#define MLEN 128
#define SLOT 65536          // HH*BB floats

// LDS layout (floats): TILE @0 (12288), PR @12288 (1792 = 28 rows x 64),
// QT @14080 (2048, persistent qW tile)
#define PR_OFF 12288
#define QT_OFF 14080
#define SM_FLOATS 16128     // 64512 bytes

typedef long long ll;
typedef float fx4 __attribute__((ext_vector_type(4)));

struct P {
    const float *x, *emb;
    const float *eWih0, *eWhh0, *ebih0, *ebhh0;
    const float *eWih1, *eWhh1, *ebih1, *ebhh1;
    const float *dWih0, *dWhh0, *dbih0, *dbhh0;
    const float *dWih1, *dWhh1, *dbih1, *dbhh1;
    const float *qW, *qb, *outW, *outb;
    float *ws;
    float *vecO, *hidO, *attnO;
};

__device__ __forceinline__ float sigf(float v) { return 1.0f / (1.0f + __expf(-v)); }

// interleaved broadcast layout: element (d, b) lives at ((d>>2)*128 + b)*4 + (d&3)
__device__ __forceinline__ int LI(int d, int b) { return ((d >> 2) * BB + b) * 4 + (d & 3); }

// scalar device-coherent relaxed ops (tiny-volume writes / reads)
__device__ __forceinline__ float ldA(const float* p) {
    return __hip_atomic_load(p, __ATOMIC_RELAXED, __HIP_MEMORY_SCOPE_AGENT);
}
__device__ __forceinline__ void stA(float* p, float v) {
    __hip_atomic_store(p, v, __ATOMIC_RELAXED, __HIP_MEMORY_SCOPE_AGENT);
}
__device__ __forceinline__ int ldAi(const int* p) {
    return __hip_atomic_load(p, __ATOMIC_RELAXED, __HIP_MEMORY_SCOPE_AGENT);
}
__device__ __forceinline__ void stAi(int* p, int v) {
    __hip_atomic_store(p, v, __ATOMIC_RELAXED, __HIP_MEMORY_SCOPE_AGENT);
}

// batched coherent loader: 8 x global_load_dwordx4 sc0 sc1 (L1/L2 bypass, 8 in
// flight), one vmcnt(0). Uses 64-bit VGPR addresses ("off" form) — the saddr
// form failed in R5 because the "s" constraint put the base in VGPRs.
// off0 = byte offset of quad 0; quad k lives at off0 + k*2048.
__device__ __forceinline__ void ld8(const float* base, int off0, fx4* o) {
    unsigned long long a0 = (unsigned long long)base + (unsigned int)off0;
    unsigned long long a1 = a0 + 4096ull;
    unsigned long long a2 = a0 + 8192ull;
    unsigned long long a3 = a0 + 12288ull;
    asm volatile(
        "global_load_dwordx4 %0, %8, off sc0 sc1\n\t"
        "global_load_dwordx4 %1, %8, off offset:2048 sc0 sc1\n\t"
        "global_load_dwordx4 %2, %9, off sc0 sc1\n\t"
        "global_load_dwordx4 %3, %9, off offset:2048 sc0 sc1\n\t"
        "global_load_dwordx4 %4, %10, off sc0 sc1\n\t"
        "global_load_dwordx4 %5, %10, off offset:2048 sc0 sc1\n\t"
        "global_load_dwordx4 %6, %11, off sc0 sc1\n\t"
        "global_load_dwordx4 %7, %11, off offset:2048 sc0 sc1\n\t"
        "s_waitcnt vmcnt(0)"
        : "=&v"(o[0]), "=&v"(o[1]), "=&v"(o[2]), "=&v"(o[3]),
          "=&v"(o[4]), "=&v"(o[5]), "=&v"(o[6]), "=&v"(o[7])
        : "v"(a0), "v"(a1), "v"(a2), "v"(a3)
        : "memory");
}

// relaxed-only two-level grid barrier (16x16), parity-slotted counters
__device__ __forceinline__ void gbar(int* W, int target) {
    __syncthreads();
    if (threadIdx.x == 0) {
        int par = target & 1;
        int g = blockIdx.x & 15;
        int* gc = W + 32 + (par * 16 + g) * 32;
        if (__hip_atomic_fetch_add(gc, 1, __ATOMIC_RELAXED, __HIP_MEMORY_SCOPE_AGENT) == 15) {
            __hip_atomic_store(gc, 0, __ATOMIC_RELAXED, __HIP_MEMORY_SCOPE_AGENT);
            int* rc = W + 1056 + par * 32;
            if (__hip_atomic_fetch_add(rc, 1, __ATOMIC_RELAXED, __HIP_MEMORY_SCOPE_AGENT) == 15) {
                __hip_atomic_store(rc, 0, __ATOMIC_RELAXED, __HIP_MEMORY_SCOPE_AGENT);
                __hip_atomic_store(W, target, __ATOMIC_RELAXED, __HIP_MEMORY_SCOPE_AGENT);
            }
        }
        while (__hip_atomic_load(W, __ATOMIC_RELAXED, __HIP_MEMORY_SCOPE_AGENT) < target)
            __builtin_amdgcn_s_sleep(2);
    }
    __syncthreads();
}

__global__ __launch_bounds__(512, 2) void kmain(P p) {
    const int tid = threadIdx.x;
    const int lane = tid & 63;
    const int wv = tid >> 6;
    const int blk = blockIdx.x;

    int* W = (int*)p.ws;
    int* tok = W + 4096;
    float* f = (float*)p.ws + 8192;
    float* eh0 = f;                       // 2 slots, interleaved LI layout
    float* eh1 = f + 2 * SLOT;            // 2 slots, interleaved
    float* inp = f + 4 * SLOT;            // ctx, interleaved
    float* qbm = f + 5 * SLOT;            // interleaved
    float* scoresB = f + 6 * SLOT;        // [256 t] interleaved (t as "d")
    float* T = f + 6 * SLOT + SLOT / 2;   // [3][512][32] emb-projection table
    float* xT = T + 3 * HH * VV;          // [256 t][2][128 b]
    float* encO = f + (SLOT / 4) * 33;    // [256 t][512 j][128 b] plain/cached

    __shared__ float smu[SM_FLOATS];
    const float4* t4 = (const float4*)smu;
    const float4* t4q = (const float4*)(smu + QT_OFF);

    const int jg = blk >> 1;              // 0..127, owns j = 4*jg..4*jg+3
    const int bh = blk & 1;
    const int b2 = bh * 64 + lane;
    int bar = 0;

    // ================= INIT =================
    {
        // zero enc h0 slot1 (read t=0) and enc h1 slot0 (read t=1)
        if (blk < 32) {
            float* dst = eh0 + SLOT;
            for (int i = blk * 512 + tid; i < SLOT; i += 32 * 512) stA(dst + i, 0.0f);
        } else if (blk < 64) {
            float* dst = eh1;
            for (int i = (blk - 32) * 512 + tid; i < SLOT; i += 32 * 512) stA(dst + i, 0.0f);
        }
        // xT transpose (write-once; later read cached)
        if (tid < 256) {
            int idx = blk * 256 + tid;
            int t = idx >> 8, c = (idx >> 7) & 1, b = idx & 127;
            stA(xT + idx, p.x[((ll)b * TT + t) * 2 + c]);
        }
        // T table: T[(g*512+j)*32+v] = dot(dWih0[g*512+j][0:512], emb[v])
        if (tid < 192) {
            int unit = blk * 192 + tid;
            int v = unit & 31, gj = unit >> 5;
            const float* wrow = p.dWih0 + (ll)gj * 1024;
            const float* erow = p.emb + (ll)v * HH;
            float acc = 0.0f;
#pragma unroll 8
            for (int d = 0; d < HH; ++d) acc = fmaf(wrow[d], erow[d], acc);
            stA(T + unit, acc);
        }
        // persistent qW tile
#pragma unroll
        for (int jl = 0; jl < 4; ++jl)
            smu[QT_OFF + jl * 512 + tid] = p.qW[((ll)(jg * 4 + jl)) * HH + tid];
        gbar(W, ++bar);
    }

    // ================= ENCODER: 257 pipelined steps =================
    for (int t = 0; t <= TT; ++t) {
        const float* h0s = eh0 + (((t + 1) & 1) ? SLOT : 0);
        float*       h0d = eh0 + ((t & 1) ? SLOT : 0);
        const float* h1s = eh1 + (((t + 1) & 1) ? SLOT : 0);
        float*       h1d = eh1 + ((t & 1) ? SLOT : 0);

        // stage round-A tile: 24 rows (hr0,hz0,hn0,ir1,iz1,in1 x 4j)
#pragma unroll
        for (int r = 0; r < 24; ++r) {
            int g = r >> 2, jl = r & 3, j = jg * 4 + jl;
            const float* src = (g < 3) ? (p.eWhh0 + (ll)(g * HH + j) * HH)
                                       : (p.eWih1 + (ll)((g - 3) * HH + j) * HH);
            smu[r * 512 + tid] = src[tid];
        }
        smu[PR_OFF + tid] = 0.0f;
        smu[PR_OFF + 512 + tid] = 0.0f;
        smu[PR_OFF + 1024 + tid] = 0.0f;
        if (tid < 256) smu[PR_OFF + 1536 + tid] = 0.0f;
        __syncthreads();

        // round A: stream h0s (wide coherent) -> l0 h-gates + l1 i-gates
        {
            const int dq0 = wv * 16;
            float acc[24];
#pragma unroll
            for (int r = 0; r < 24; ++r) acc[r] = 0.0f;
            for (int half = 0; half < 2; ++half) {
                fx4 av4[8];
                ld8(h0s, ((dq0 + half * 8) * BB + b2) * 16, av4);
#pragma unroll
                for (int q = 0; q < 8; ++q) {
                    const int qq = dq0 + half * 8 + q;
#pragma unroll
                    for (int r = 0; r < 24; ++r) {
                        float4 w = t4[r * 128 + qq];
                        acc[r] = fmaf(w.x, av4[q].x, acc[r]);
                        acc[r] = fmaf(w.y, av4[q].y, acc[r]);
                        acc[r] = fmaf(w.z, av4[q].z, acc[r]);
                        acc[r] = fmaf(w.w, av4[q].w, acc[r]);
                    }
                }
            }
#pragma unroll
            for (int r = 0; r < 24; ++r)
                unsafeAtomicAdd(&smu[PR_OFF + r * 64 + lane], acc[r]);
        }
        __syncthreads();

        // stage round-B tile: 12 rows (hr1,hz1,hn1 x 4j)
#pragma unroll
        for (int r = 0; r < 12; ++r) {
            int g = r >> 2, jl = r & 3, j = jg * 4 + jl;
            smu[r * 512 + tid] = p.eWhh1[(ll)(g * HH + j) * HH + tid];
        }
        __syncthreads();

        // round B: stream h1s (wide coherent) -> l1 h-gates
        {
            const int dq0 = wv * 16;
            float acc[12];
#pragma unroll
            for (int r = 0; r < 12; ++r) acc[r] = 0.0f;
            for (int half = 0; half < 2; ++half) {
                fx4 av4[8];
                ld8(h1s, ((dq0 + half * 8) * BB + b2) * 16, av4);
#pragma unroll
                for (int q = 0; q < 8; ++q) {
                    const int qq = dq0 + half * 8 + q;
#pragma unroll
                    for (int r = 0; r < 12; ++r) {
                        float4 w = t4[r * 128 + qq];
                        acc[r] = fmaf(w.x, av4[q].x, acc[r]);
                        acc[r] = fmaf(w.y, av4[q].y, acc[r]);
                        acc[r] = fmaf(w.z, av4[q].z, acc[r]);
                        acc[r] = fmaf(w.w, av4[q].w, acc[r]);
                    }
                }
            }
#pragma unroll
            for (int r = 0; r < 12; ++r) {
                int g = r >> 2;
                int prow = (g < 2) ? (12 + g * 4) : 24;
                unsafeAtomicAdd(&smu[PR_OFF + (prow + (r & 3)) * 64 + lane], acc[r]);
            }
        }
        __syncthreads();

        // finalize
        if (wv < 4) {
            int jl = wv, j = jg * 4 + jl;
            float* pr = smu + PR_OFF;
            if (t < TT) {
                float hr = pr[(0 + jl) * 64 + lane] + p.ebhh0[j];
                float hz = pr[(4 + jl) * 64 + lane] + p.ebhh0[HH + j];
                float hn = pr[(8 + jl) * 64 + lane] + p.ebhh0[2 * HH + j];
                float x0 = xT[t * 256 + b2], x1 = xT[t * 256 + 128 + b2];
                float ir = fmaf(p.eWih0[j * 2], x0, fmaf(p.eWih0[j * 2 + 1], x1, p.ebih0[j]));
                float iz = fmaf(p.eWih0[(HH + j) * 2], x0, fmaf(p.eWih0[(HH + j) * 2 + 1], x1, p.ebih0[HH + j]));
                float in_ = fmaf(p.eWih0[(2 * HH + j) * 2], x0, fmaf(p.eWih0[(2 * HH + j) * 2 + 1], x1, p.ebih0[2 * HH + j]));
                float r = sigf(ir + hr), z = sigf(iz + hz);
                float n = tanhf(in_ + r * hn);
                float hp = ldA(h0s + LI(j, b2));
                stA(h0d + LI(j, b2), (1.0f - z) * n + z * hp);
            }
            if (t >= 1) {
                float rs = pr[(12 + jl) * 64 + lane] + p.ebih1[j] + p.ebhh1[j];
                float zs = pr[(16 + jl) * 64 + lane] + p.ebih1[HH + j] + p.ebhh1[HH + j];
                float in1 = pr[(20 + jl) * 64 + lane] + p.ebih1[2 * HH + j];
                float hn1 = pr[(24 + jl) * 64 + lane] + p.ebhh1[2 * HH + j];
                float r = sigf(rs), z = sigf(zs);
                float n = tanhf(in1 + r * hn1);
                float hp = ldA(h1s + LI(j, b2));
                float hv = (1.0f - z) * n + z * hp;
                stA(h1d + LI(j, b2), hv);
                stA(encO + ((ll)(t - 1) * HH + j) * BB + b2, hv);  // plain layout
            }
        }
        gbar(W, ++bar);
    }

    // ================= DEC-INIT: query from enc h1 final (slot0), tok=0 =================
    {
        const float* h1c = eh1;  // slot 0
        if (tid < 256) smu[PR_OFF + tid] = 0.0f;
        __syncthreads();
        {
            const int dq0 = wv * 16;
            float acc[4] = {0, 0, 0, 0};
            for (int half = 0; half < 2; ++half) {
                fx4 av4[8];
                ld8(h1c, ((dq0 + half * 8) * BB + b2) * 16, av4);
#pragma unroll
                for (int q = 0; q < 8; ++q) {
                    const int qq = dq0 + half * 8 + q;
#pragma unroll
                    for (int jl = 0; jl < 4; ++jl) {
                        float4 w = t4q[jl * 128 + qq];
                        acc[jl] = fmaf(w.x, av4[q].x, acc[jl]);
                        acc[jl] = fmaf(w.y, av4[q].y, acc[jl]);
                        acc[jl] = fmaf(w.z, av4[q].z, acc[jl]);
                        acc[jl] = fmaf(w.w, av4[q].w, acc[jl]);
                    }
                }
            }
#pragma unroll
            for (int jl = 0; jl < 4; ++jl)
                unsafeAtomicAdd(&smu[PR_OFF + jl * 64 + lane], acc[jl]);
        }
        __syncthreads();
        if (wv < 4) {
            int j = jg * 4 + wv;
            stA(qbm + LI(j, b2), smu[PR_OFF + wv * 64 + lane] + p.qb[j]);
        }
        if (blk == 128 && tid < BB) stAi(tok + tid, 0);
        gbar(W, ++bar);
    }

    // ================= DECODER: 128 steps x 5 phases =================
    for (int s = 0; s < MLEN; ++s) {
        const float* h0s = eh0 + (((s + 1) & 1) ? SLOT : 0);
        float*       g0d = eh0 + ((s & 1) ? SLOT : 0);
        const float* h1s = eh1 + ((s & 1) ? SLOT : 0);
        float*       h1d = eh1 + (((s + 1) & 1) ? SLOT : 0);

        // --- A1: scores (blocks 0..127) ---
        if (blk < 128) {
            const int tq4 = jg * 4;  // t-quad base
            if (tid < 256) smu[PR_OFF + tid] = 0.0f;
            __syncthreads();
            const int jq0 = wv * 16;
            float acc[4] = {0, 0, 0, 0};
            for (int half = 0; half < 2; ++half) {
                fx4 qv4[8];
                ld8(qbm, ((jq0 + half * 8) * BB + b2) * 16, qv4);
#pragma unroll
                for (int q = 0; q < 8; ++q) {
                    const float* qf = (const float*)&qv4[q];
#pragma unroll
                    for (int e = 0; e < 4; ++e) {
                        int jj = (jq0 + half * 8 + q) * 4 + e;
                        float qv = qf[e];
#pragma unroll
                        for (int tt = 0; tt < 4; ++tt)
                            acc[tt] = fmaf(qv, encO[((ll)(tq4 + tt) * HH + jj) * BB + b2], acc[tt]);
                    }
                }
            }
#pragma unroll
            for (int tt = 0; tt < 4; ++tt)
                unsafeAtomicAdd(&smu[PR_OFF + tt * 64 + lane], acc[tt]);
            __syncthreads();
            if (wv < 4)
                stA(scoresB + LI(tq4 + wv, b2), smu[PR_OFF + wv * 64 + lane]);
        }
        gbar(W, ++bar);

        // --- A2: softmax + context (all 256 blocks); blocks<16 write attnO ---
        {
            const int d0 = jg * 4;  // ctx dims
            float sv[32];
            {
                fx4 sv4[8];
                ld8(scoresB, ((wv * 8) * BB + b2) * 16, sv4);
#pragma unroll
                for (int q = 0; q < 8; ++q) {
                    const float* sf = (const float*)&sv4[q];
#pragma unroll
                    for (int e = 0; e < 4; ++e) sv[q * 4 + e] = sf[e];
                }
            }
            if (tid < 256) smu[PR_OFF + tid] = 0.0f;
            float mp = sv[0];
#pragma unroll
            for (int k = 1; k < 32; ++k) mp = fmaxf(mp, sv[k]);
            smu[wv * 64 + lane] = mp;
            __syncthreads();
            float m = smu[lane];
#pragma unroll
            for (int u = 1; u < 8; ++u) m = fmaxf(m, smu[u * 64 + lane]);
            float e[32], lp = 0.0f;
#pragma unroll
            for (int k = 0; k < 32; ++k) { e[k] = __expf(sv[k] - m); lp += e[k]; }
            smu[512 + wv * 64 + lane] = lp;
            __syncthreads();
            float l = smu[512 + lane];
#pragma unroll
            for (int u = 1; u < 8; ++u) l += smu[512 + u * 64 + lane];
            float rl = 1.0f / l;
            if (blk < 16 && wv == jg) {
#pragma unroll
                for (int k = 0; k < 32; ++k) smu[2048 + k * 65 + lane] = e[k] * rl;
            }
            float c4[4] = {0, 0, 0, 0};
            for (int k = 0; k < 32; ++k) {
                int t = wv * 32 + k;
                const float* Ep = encO + ((ll)t * HH + d0) * BB + b2;
                c4[0] = fmaf(e[k], Ep[0], c4[0]);
                c4[1] = fmaf(e[k], Ep[BB], c4[1]);
                c4[2] = fmaf(e[k], Ep[2 * BB], c4[2]);
                c4[3] = fmaf(e[k], Ep[3 * BB], c4[3]);
            }
#pragma unroll
            for (int kk = 0; kk < 4; ++kk)
                unsafeAtomicAdd(&smu[PR_OFF + kk * 64 + lane], c4[kk]);
            __syncthreads();
            if (tid < 256) {
                int kk = tid >> 6, ln = tid & 63;
                float l2 = smu[512 + ln];
#pragma unroll
                for (int u = 1; u < 8; ++u) l2 += smu[512 + u * 64 + ln];
                float val = smu[PR_OFF + kk * 64 + ln] / l2;
                stA(inp + LI(d0 + kk, bh * 64 + ln), val);
            }
            if (blk < 16) {
                for (int r = 0; r < 4; ++r) {
                    int it = r * 512 + tid;
                    int tl = it >> 6, bi = it & 63;
                    p.attnO[((ll)(bh * 64 + bi) * MLEN + s) * TT + jg * 32 + tl] =
                        smu[2048 + tl * 65 + bi];
                }
            }
        }
        gbar(W, ++bar);

        // --- G0: decoder gru layer0 (streams: ctx 512 + h0 512) ---
        {
#pragma unroll
            for (int r = 0; r < 12; ++r) {
                int g = r >> 2, jl = r & 3, j = jg * 4 + jl;
                smu[r * 1024 + tid] = p.dWih0[(ll)(g * HH + j) * 1024 + 512 + tid];
                smu[r * 1024 + 512 + tid] = p.dWhh0[(ll)(g * HH + j) * HH + tid];
            }
            smu[PR_OFF + tid] = 0.0f;
            smu[PR_OFF + 512 + tid] = 0.0f;
            __syncthreads();
            const int ctxw = (wv < 4);
            const float* stream = ctxw ? inp : h0s;
            const int dq0 = (wv & 3) * 32;
            const int tbq = ctxw ? 0 : 128;
            float acc[12];
#pragma unroll
            for (int r = 0; r < 12; ++r) acc[r] = 0.0f;
            for (int half = 0; half < 4; ++half) {
                fx4 av4[8];
                ld8(stream, ((dq0 + half * 8) * BB + b2) * 16, av4);
#pragma unroll
                for (int q = 0; q < 8; ++q) {
                    const int qq = tbq + dq0 + half * 8 + q;
#pragma unroll
                    for (int r = 0; r < 12; ++r) {
                        float4 w = t4[r * 256 + qq];
                        acc[r] = fmaf(w.x, av4[q].x, acc[r]);
                        acc[r] = fmaf(w.y, av4[q].y, acc[r]);
                        acc[r] = fmaf(w.z, av4[q].z, acc[r]);
                        acc[r] = fmaf(w.w, av4[q].w, acc[r]);
                    }
                }
            }
#pragma unroll
            for (int r = 0; r < 12; ++r) {
                int g = r >> 2;
                int prow = (g < 2) ? g * 4 : (ctxw ? 8 : 12);
                unsafeAtomicAdd(&smu[PR_OFF + (prow + (r & 3)) * 64 + lane], acc[r]);
            }
            __syncthreads();
            if (wv < 4) {
                int jl = wv, j = jg * 4 + jl;
                float* pr = smu + PR_OFF;
                int tokb = ldAi(tok + b2);
                float rs = T[(ll)j * 32 + tokb] + pr[(0 + jl) * 64 + lane] + p.dbih0[j] + p.dbhh0[j];
                float zs = T[(ll)(HH + j) * 32 + tokb] + pr[(4 + jl) * 64 + lane] + p.dbih0[HH + j] + p.dbhh0[HH + j];
                float ins = T[(ll)(2 * HH + j) * 32 + tokb] + pr[(8 + jl) * 64 + lane] + p.dbih0[2 * HH + j];
                float hns = pr[(12 + jl) * 64 + lane] + p.dbhh0[2 * HH + j];
                float r = sigf(rs), z = sigf(zs);
                float n = tanhf(ins + r * hns);
                float hp = ldA(h0s + LI(j, b2));
                stA(g0d + LI(j, b2), (1.0f - z) * n + z * hp);
            }
        }
        gbar(W, ++bar);

        // --- G1: decoder gru layer1 (streams: g0 512 + h1 512) ---
        {
#pragma unroll
            for (int r = 0; r < 12; ++r) {
                int g = r >> 2, jl = r & 3, j = jg * 4 + jl;
                smu[r * 1024 + tid] = p.dWih1[(ll)(g * HH + j) * HH + tid];
                smu[r * 1024 + 512 + tid] = p.dWhh1[(ll)(g * HH + j) * HH + tid];
            }
            smu[PR_OFF + tid] = 0.0f;
            smu[PR_OFF + 512 + tid] = 0.0f;
            __syncthreads();
            const int iw = (wv < 4);
            const float* stream = iw ? g0d : h1s;
            const int dq0 = (wv & 3) * 32;
            const int tbq = iw ? 0 : 128;
            float acc[12];
#pragma unroll
            for (int r = 0; r < 12; ++r) acc[r] = 0.0f;
            for (int half = 0; half < 4; ++half) {
                fx4 av4[8];
                ld8(stream, ((dq0 + half * 8) * BB + b2) * 16, av4);
#pragma unroll
                for (int q = 0; q < 8; ++q) {
                    const int qq = tbq + dq0 + half * 8 + q;
#pragma unroll
                    for (int r = 0; r < 12; ++r) {
                        float4 w = t4[r * 256 + qq];
                        acc[r] = fmaf(w.x, av4[q].x, acc[r]);
                        acc[r] = fmaf(w.y, av4[q].y, acc[r]);
                        acc[r] = fmaf(w.z, av4[q].z, acc[r]);
                        acc[r] = fmaf(w.w, av4[q].w, acc[r]);
                    }
                }
            }
#pragma unroll
            for (int r = 0; r < 12; ++r) {
                int g = r >> 2;
                int prow = (g < 2) ? g * 4 : (iw ? 8 : 12);
                unsafeAtomicAdd(&smu[PR_OFF + (prow + (r & 3)) * 64 + lane], acc[r]);
            }
            __syncthreads();
            if (wv < 4) {
                int jl = wv, j = jg * 4 + jl;
                float* pr = smu + PR_OFF;
                float rs = pr[(0 + jl) * 64 + lane] + p.dbih1[j] + p.dbhh1[j];
                float zs = pr[(4 + jl) * 64 + lane] + p.dbih1[HH + j] + p.dbhh1[HH + j];
                float ins = pr[(8 + jl) * 64 + lane] + p.dbih1[2 * HH + j];
                float hns = pr[(12 + jl) * 64 + lane] + p.dbhh1[2 * HH + j];
                float r = sigf(rs), z = sigf(zs);
                float n = tanhf(ins + r * hns);
                float hp = ldA(h1s + LI(j, b2));
                stA(h1d + LI(j, b2), (1.0f - z) * n + z * hp);
            }
        }
        gbar(W, ++bar);

        // --- D: query (all blocks) + logits/argmax/tok (blocks 128..135) ---
        {
            const float* h1c = h1d;
            if (tid < 256) smu[PR_OFF + tid] = 0.0f;
            __syncthreads();
            {
                const int dq0 = wv * 16;
                float acc[4] = {0, 0, 0, 0};
                for (int half = 0; half < 2; ++half) {
                    fx4 av4[8];
                    ld8(h1c, ((dq0 + half * 8) * BB + b2) * 16, av4);
#pragma unroll
                    for (int q = 0; q < 8; ++q) {
                        const int qq = dq0 + half * 8 + q;
#pragma unroll
                        for (int jl = 0; jl < 4; ++jl) {
                            float4 w = t4q[jl * 128 + qq];
                            acc[jl] = fmaf(w.x, av4[q].x, acc[jl]);
                            acc[jl] = fmaf(w.y, av4[q].y, acc[jl]);
                            acc[jl] = fmaf(w.z, av4[q].z, acc[jl]);
                            acc[jl] = fmaf(w.w, av4[q].w, acc[jl]);
                        }
                    }
                }
#pragma unroll
                for (int jl = 0; jl < 4; ++jl)
                    unsafeAtomicAdd(&smu[PR_OFF + jl * 64 + lane], acc[jl]);
            }
            __syncthreads();
            if (wv < 4) {
                int j = jg * 4 + wv;
                stA(qbm + LI(j, b2), smu[PR_OFF + wv * 64 + lane] + p.qb[j]);
            }
            if (blk >= 128 && blk < 136) {
                __syncthreads();
                const int bb = (blk - 128) * 16;
                // stage g1 slice [512 d][16 b] into smu[0..8192)
#pragma unroll
                for (int i = 0; i < 16; ++i) {
                    int ff = i * 512 + tid;
                    int d = ff >> 4, bi = ff & 15;
                    smu[ff] = ldA(h1c + LI(d, bb + bi));
                }
                __syncthreads();
                const int bl = wv * 2 + (lane >> 5);
                const int v = lane & 31;
                float acc = 0.0f;
                for (int d4 = 0; d4 < 128; ++d4) {
                    float4 w4 = *(const float4*)(p.outW + (ll)v * HH + d4 * 4);
                    acc = fmaf(w4.x, smu[(d4 * 4 + 0) * 16 + bl], acc);
                    acc = fmaf(w4.y, smu[(d4 * 4 + 1) * 16 + bl], acc);
                    acc = fmaf(w4.z, smu[(d4 * 4 + 2) * 16 + bl], acc);
                    acc = fmaf(w4.w, smu[(d4 * 4 + 3) * 16 + bl], acc);
                }
                acc += p.outb[v];
                p.vecO[((ll)(bb + bl) * MLEN + s) * VV + v] = acc;
                smu[8704 + wv * 64 + lane] = acc;
                if (v == 0) {  // first-max scan (jnp.argmax semantics)
                    int base = 8704 + wv * 64 + (lane >> 5) * 32;
                    float best = smu[base];
                    int bi = 0;
#pragma unroll
                    for (int u = 1; u < 32; ++u) {
                        float val = smu[base + u];
                        if (val > best) { best = val; bi = u; }
                    }
                    stAi(tok + bb + bl, bi);
                }
            }
        }
        gbar(W, ++bar);
    }

    // ================= final hidden [2][128][512] =================
    {
        int idx = blk * 512 + tid;
        int l = idx >> 16, rr = idx & 65535;
        int b = rr >> 9, h = rr & 511;
        const float* src = l ? eh1 : (eh0 + SLOT);  // dh1 final slot0, dh0 final slot1
        p.hidO[idx] = ldA(src + LI(h, b));
    }
}

extern "C" void kernel_launch(void* const* d_in, const int* in_sizes, int n_in,
                              void* d_out, int out_size, void* d_ws, size_t ws_size,
                              hipStream_t stream) {
    (void)in_sizes; (void)n_in; (void)out_size; (void)ws_size;
    P prm;
    prm.x     = (const float*)d_in[0];
    prm.emb   = (const float*)d_in[1];
    prm.eWih0 = (const float*)d_in[2];
    prm.eWhh0 = (const float*)d_in[3];
    prm.ebih0 = (const float*)d_in[4];
    prm.ebhh0 = (const float*)d_in[5];
    prm.eWih1 = (const float*)d_in[6];
    prm.eWhh1 = (const float*)d_in[7];
    prm.ebih1 = (const float*)d_in[8];
    prm.ebhh1 = (const float*)d_in[9];
    prm.dWih0 = (const float*)d_in[10];
    prm.dWhh0 = (const float*)d_in[11];
    prm.dbih0 = (const float*)d_in[12];
    prm.dbhh0 = (const float*)d_in[13];
    prm.dWih1 = (const float*)d_in[14];
    prm.dWhh1 = (const float*)d_in[15];
    prm.dbih1 = (const float*)d_in[16];
    prm.dbhh1 = (const float*)d_in[17];
    prm.qW    = (const float*)d_in[18];
    prm.qb    = (const float*)d_in[19];
    prm.outW  = (const float*)d_in[20];
    prm.outb  = (const float*)d_in[21];
    prm.ws    = (float*)d_ws;
    prm.vecO  = (float*)d_out;
    prm.hidO  = prm.vecO + (ll)BB * MLEN * VV;
    prm.attnO = prm.hidO + (ll)2 * BB * HH;

    hipMemsetAsync(d_ws, 0, 16384, stream);  // barrier gen + tree counters
    void* args[] = { &prm };
    hipLaunchCooperativeKernel((void*)kmain, dim3(256), dim3(512), args, 0, stream);
}